// Round 5
// baseline (754.439 us; speedup 1.0000x reference)
//
#include <hip/hip_runtime.h>
#include <math.h>
#include <float.h>

#define PH 7
#define PW 7
#define RLEN 32   // ints per roi in workspace

// ---- exact integer emulation of the reference's fast-math f32 binning ----
// bin = RN_f32(roi * RN_f32(1/7));  RN_f32(1/7) = 9586981 * 2^-26
#define C7 9586981LL

__device__ __forceinline__ long long round24(long long v) {
    if (v == 0) return 0;
    int L = 64 - __clzll((unsigned long long)v);
    int sh = L - 24;
    if (sh <= 0) return v;
    long long rem  = v & ((1LL << sh) - 1);
    long long base = v >> sh;
    long long half = 1LL << (sh - 1);
    if (rem > half || (rem == half && (base & 1))) base++;
    return base << sh;
}
__device__ __forceinline__ long long bin_q26(int roi) {
    return round24((long long)roi * C7);
}
__device__ __forceinline__ int floor_k(long long b26, int k) {
    long long v = round24((long long)k * b26);
    return (int)(v >> 26);
}
__device__ __forceinline__ int ceil_k(long long b26, int k) {
    long long v = round24((long long)k * b26);
    return (int)((v + ((1LL << 26) - 1)) >> 26);
}

// Per-ROI bound precompute: ws layout per roi (RLEN ints):
// [0]=b, [1..7]=hstart, [8..14]=hend, [15..21]=wstart, [22..28]=wend (clipped)
__global__ void roi_bounds_kernel(const float* __restrict__ rois,
                                  int* __restrict__ wsbuf, int R) {
    int r = blockIdx.x * blockDim.x + threadIdx.x;
    if (r >= R) return;
    const int H = 64, W = 64;
    const float* roi = rois + r * 5;
    int b  = (int)roi[0];                    // astype(int32) = trunc
    int x1 = (int)rintf(roi[1] * 0.0625f);   // exact mult; RNE = jnp.round
    int y1 = (int)rintf(roi[2] * 0.0625f);
    int x2 = (int)rintf(roi[3] * 0.0625f);
    int y2 = (int)rintf(roi[4] * 0.0625f);

    int roi_w = max(x2 - x1 + 1, 1);
    int roi_h = max(y2 - y1 + 1, 1);
    long long bh = bin_q26(roi_h);
    long long bw = bin_q26(roi_w);

    int* o = wsbuf + r * RLEN;
    o[0] = b;
    #pragma unroll
    for (int i = 0; i < PH; ++i) {
        int hs = min(max(y1 + floor_k(bh, i),     0), H);
        int he = min(max(y1 + ceil_k (bh, i + 1), 0), H);
        int wst = min(max(x1 + floor_k(bw, i),     0), W);
        int wen = min(max(x1 + ceil_k (bw, i + 1), 0), W);
        o[1 + i]  = hs;
        o[8 + i]  = he;
        o[15 + i] = wst;
        o[22 + i] = wen;
    }
}

// Main: one wave per (roi, channel); lane = w column (W == 64 == wavefront).
// Block = 256 threads = 4 waves = 4 consecutive channels of one roi.
__global__ __launch_bounds__(256) void roipool_main(
        const float* __restrict__ features,
        const int* __restrict__ wsbuf,
        float* __restrict__ out) {
    __shared__ float cm[4][PH][66];   // padded: avoids 7-way bank conflict in reduce
    __shared__ int sb[29];

    int r    = blockIdx.x >> 7;       // 128 channel-groups of 4
    int cg   = blockIdx.x & 127;
    int wv   = threadIdx.x >> 6;
    int lane = threadIdx.x & 63;
    int c    = (cg << 2) + wv;

    const int* B = wsbuf + r * RLEN;
    if (threadIdx.x < 29) sb[threadIdx.x] = B[threadIdx.x];

    int b   = B[0];
    int ws0 = B[15];
    int we6 = B[28];
    bool w_in = (lane >= ws0) && (lane < we6);

    const float* fmap = features + ((size_t)((b << 9) + c) << 12); // *512, *4096

    #pragma unroll
    for (int ph = 0; ph < PH; ++ph) {
        int hs = B[1 + ph], he = B[8 + ph];
        float m = -FLT_MAX;
        for (int h = hs; h < he; ++h) {          // scalar-uniform loop
            float v = -FLT_MAX;
            if (w_in) v = fmap[(h << 6) + lane]; // coalesced 64-lane row load
            m = fmaxf(m, v);
        }
        cm[wv][ph][lane] = m;
    }
    __syncthreads();

    if (lane < 49) {
        int ph = lane / 7;
        int pw = lane - ph * 7;
        int hs  = sb[1 + ph],  he  = sb[8 + ph];
        int wst = sb[15 + pw], wen = sb[22 + pw];
        float m = -FLT_MAX;
        for (int w = wst; w < wen; ++w)
            m = fmaxf(m, cm[wv][ph][w]);
        bool empty = (he <= hs) || (wen <= wst);
        float res = empty ? 0.0f : m;
        __builtin_nontemporal_store(res, &out[(((size_t)r << 9) + c) * 49 + lane]);
    }
}

extern "C" void kernel_launch(void* const* d_in, const int* in_sizes, int n_in,
                              void* d_out, int out_size, void* d_ws, size_t ws_size,
                              hipStream_t stream) {
    const float* features = (const float*)d_in[0];
    const float* rois     = (const float*)d_in[1];
    float* out = (float*)d_out;
    int* wsbuf = (int*)d_ws;

    int R = in_sizes[1] / 5;   // 2000

    roi_bounds_kernel<<<(R + 255) / 256, 256, 0, stream>>>(rois, wsbuf, R);
    roipool_main<<<R * 128, 256, 0, stream>>>(features, wsbuf, out);
}

// Round 6
// 450.705 us; speedup vs baseline: 1.6739x; 1.6739x over previous
//
#include <hip/hip_runtime.h>
#include <math.h>
#include <float.h>

#define PH 7
#define RLEN 32   // ints per roi in workspace

// ---- exact integer emulation of the reference's fast-math f32 binning ----
// bin = RN_f32(roi * RN_f32(1/7));  RN_f32(1/7) = 9586981 * 2^-26
#define C7 9586981LL

__device__ __forceinline__ long long round24(long long v) {
    if (v == 0) return 0;
    int L = 64 - __clzll((unsigned long long)v);
    int sh = L - 24;
    if (sh <= 0) return v;
    long long rem  = v & ((1LL << sh) - 1);
    long long base = v >> sh;
    long long half = 1LL << (sh - 1);
    if (rem > half || (rem == half && (base & 1))) base++;
    return base << sh;
}
__device__ __forceinline__ long long bin_q26(int roi) {
    return round24((long long)roi * C7);
}
__device__ __forceinline__ int floor_k(long long b26, int k) {
    long long v = round24((long long)k * b26);
    return (int)(v >> 26);
}
__device__ __forceinline__ int ceil_k(long long b26, int k) {
    long long v = round24((long long)k * b26);
    return (int)((v + ((1LL << 26) - 1)) >> 26);
}

// Per-ROI bounds: [0]=b, [1..7]=hstart, [8..14]=hend, [15..21]=wstart, [22..28]=wend
__global__ void roi_bounds_kernel(const float* __restrict__ rois,
                                  int* __restrict__ wsbuf, int R) {
    int r = blockIdx.x * blockDim.x + threadIdx.x;
    if (r >= R) return;
    const int H = 64, W = 64;
    const float* roi = rois + r * 5;
    int b  = (int)roi[0];
    int x1 = (int)rintf(roi[1] * 0.0625f);
    int y1 = (int)rintf(roi[2] * 0.0625f);
    int x2 = (int)rintf(roi[3] * 0.0625f);
    int y2 = (int)rintf(roi[4] * 0.0625f);

    int roi_w = max(x2 - x1 + 1, 1);
    int roi_h = max(y2 - y1 + 1, 1);
    long long bh = bin_q26(roi_h);
    long long bw = bin_q26(roi_w);

    int* o = wsbuf + r * RLEN;
    o[0] = b;
    #pragma unroll
    for (int i = 0; i < PH; ++i) {
        o[1 + i]  = min(max(y1 + floor_k(bh, i),     0), H);
        o[8 + i]  = min(max(y1 + ceil_k (bh, i + 1), 0), H);
        o[15 + i] = min(max(x1 + floor_k(bw, i),     0), W);
        o[22 + i] = min(max(x1 + ceil_k (bw, i + 1), 0), W);
    }
}

// One wave per (roi, 4 channels); lane = w column. Block = 4 waves = 16 channels.
// Grid = R * 32.  4 independent row loads in flight per iteration (MLP).
__global__ __launch_bounds__(256) void roipool_main(
        const float* __restrict__ features,
        const int* __restrict__ wsbuf,
        float* __restrict__ out) {
    __shared__ float cm[16][PH][66];   // 29.5 KB, padded stride
    __shared__ int sb[29];

    int r    = blockIdx.x >> 5;
    int cg   = blockIdx.x & 31;
    int wv   = threadIdx.x >> 6;
    int lane = threadIdx.x & 63;
    int c0   = (cg << 4) + (wv << 2);   // first of this wave's 4 channels

    const int* B = wsbuf + r * RLEN;
    if (threadIdx.x < 29) sb[threadIdx.x] = B[threadIdx.x];

    int b = B[0];
    const float* p0 = features + ((size_t)((b << 9) + c0) << 12);
    const float* p1 = p0 + 4096;
    const float* p2 = p0 + 8192;
    const float* p3 = p0 + 12288;

    #pragma unroll
    for (int ph = 0; ph < PH; ++ph) {
        int hs = B[1 + ph], he = B[8 + ph];   // uniform scalar loads
        float m0 = -FLT_MAX, m1 = -FLT_MAX, m2 = -FLT_MAX, m3 = -FLT_MAX;
        for (int h = hs; h < he; ++h) {
            int off = (h << 6) + lane;
            float v0 = p0[off];   // 4 independent loads -> 4 outstanding
            float v1 = p1[off];
            float v2 = p2[off];
            float v3 = p3[off];
            m0 = fmaxf(m0, v0);
            m1 = fmaxf(m1, v1);
            m2 = fmaxf(m2, v2);
            m3 = fmaxf(m3, v3);
        }
        int ch = wv << 2;
        cm[ch + 0][ph][lane] = m0;
        cm[ch + 1][ph][lane] = m1;
        cm[ch + 2][ph][lane] = m2;
        cm[ch + 3][ph][lane] = m3;
    }
    __syncthreads();

    // 16 ch * 49 bins = 784 contiguous outputs per block
    size_t obase = ((size_t)(r << 9) + (cg << 4)) * 49;
    for (int f = threadIdx.x; f < 16 * 49; f += 256) {
        int ch = f / 49;
        int i  = f - ch * 49;
        int ph = i / 7;
        int pw = i - ph * 7;
        int hs  = sb[1 + ph],  he  = sb[8 + ph];
        int wst = sb[15 + pw], wen = sb[22 + pw];
        float m = -FLT_MAX;
        for (int w = wst; w < wen; ++w)
            m = fmaxf(m, cm[ch][ph][w]);
        bool empty = (he <= hs) || (wen <= wst);
        __builtin_nontemporal_store(empty ? 0.0f : m, &out[obase + f]);
    }
}

extern "C" void kernel_launch(void* const* d_in, const int* in_sizes, int n_in,
                              void* d_out, int out_size, void* d_ws, size_t ws_size,
                              hipStream_t stream) {
    const float* features = (const float*)d_in[0];
    const float* rois     = (const float*)d_in[1];
    float* out = (float*)d_out;
    int* wsbuf = (int*)d_ws;

    int R = in_sizes[1] / 5;   // 2000

    roi_bounds_kernel<<<(R + 255) / 256, 256, 0, stream>>>(rois, wsbuf, R);
    roipool_main<<<R * 32, 256, 0, stream>>>(features, wsbuf, out);
}

// Round 7
// 440.824 us; speedup vs baseline: 1.7114x; 1.0224x over previous
//
#include <hip/hip_runtime.h>
#include <math.h>
#include <float.h>

#define PH 7
#define RLEN 32   // ints per roi in workspace

// ---- exact integer emulation of the reference's fast-math f32 binning ----
// bin = RN_f32(roi * RN_f32(1/7));  RN_f32(1/7) = 9586981 * 2^-26
#define C7 9586981LL

__device__ __forceinline__ long long round24(long long v) {
    if (v == 0) return 0;
    int L = 64 - __clzll((unsigned long long)v);
    int sh = L - 24;
    if (sh <= 0) return v;
    long long rem  = v & ((1LL << sh) - 1);
    long long base = v >> sh;
    long long half = 1LL << (sh - 1);
    if (rem > half || (rem == half && (base & 1))) base++;
    return base << sh;
}
__device__ __forceinline__ long long bin_q26(int roi) {
    return round24((long long)roi * C7);
}
__device__ __forceinline__ int floor_k(long long b26, int k) {
    long long v = round24((long long)k * b26);
    return (int)(v >> 26);
}
__device__ __forceinline__ int ceil_k(long long b26, int k) {
    long long v = round24((long long)k * b26);
    return (int)((v + ((1LL << 26) - 1)) >> 26);
}

// Per-ROI bounds: [0]=b, [1..7]=hstart, [8..14]=hend, [15..21]=wstart, [22..28]=wend
__global__ void roi_bounds_kernel(const float* __restrict__ rois,
                                  int* __restrict__ wsbuf, int R) {
    int r = blockIdx.x * blockDim.x + threadIdx.x;
    if (r >= R) return;
    const int H = 64, W = 64;
    const float* roi = rois + r * 5;
    int b  = (int)roi[0];
    int x1 = (int)rintf(roi[1] * 0.0625f);
    int y1 = (int)rintf(roi[2] * 0.0625f);
    int x2 = (int)rintf(roi[3] * 0.0625f);
    int y2 = (int)rintf(roi[4] * 0.0625f);

    int roi_w = max(x2 - x1 + 1, 1);
    int roi_h = max(y2 - y1 + 1, 1);
    long long bh = bin_q26(roi_h);
    long long bw = bin_q26(roi_w);

    int* o = wsbuf + r * RLEN;
    o[0] = b;
    #pragma unroll
    for (int i = 0; i < PH; ++i) {
        o[1 + i]  = min(max(y1 + floor_k(bh, i),     0), H);
        o[8 + i]  = min(max(y1 + ceil_k (bh, i + 1), 0), H);
        o[15 + i] = min(max(x1 + floor_k(bw, i),     0), W);
        o[22 + i] = min(max(x1 + ceil_k (bw, i + 1), 0), W);
    }
}

__device__ __forceinline__ float4 max4(float4 a, float4 b) {
    float4 r;
    r.x = fmaxf(a.x, b.x); r.y = fmaxf(a.y, b.y);
    r.z = fmaxf(a.z, b.z); r.w = fmaxf(a.w, b.w);
    return r;
}

// One wave = 4 channels of one roi. lane = (chsub 0..3) * 16 + (colquad 0..15).
// One dwordx4 load per row-iteration covers a full 64-col row x 4 channels.
// Block = 128 threads = 2 waves = 8 channels; waves independent (no barrier).
__global__ __launch_bounds__(128) void roipool_main(
        const float* __restrict__ features,
        const int* __restrict__ wsbuf,
        float* __restrict__ out) {
    __shared__ float cm[8][PH][64];   // 14 KB

    int r    = blockIdx.x >> 6;       // 64 channel-groups of 8
    int cg   = blockIdx.x & 63;
    int wv   = threadIdx.x >> 6;      // 0..1
    int lane = threadIdx.x & 63;
    int chsub = lane >> 4;            // channel within wave's quad (uniform per 16 lanes)
    int cq    = lane & 15;            // column quad
    int c0   = (cg << 3) + (wv << 2); // wave's first channel

    const int* B = wsbuf + r * RLEN;  // uniform -> scalar loads
    int b = B[0];

    const float4* f4 = (const float4*)features;
    // float4 index: (b*512 + c0 + chsub)*1024 + cq ; row h adds h*16
    int base = (((b << 9) + c0 + chsub) << 10) | cq;

    int chl = (wv << 2) + chsub;

    #pragma unroll
    for (int ph = 0; ph < PH; ++ph) {
        int hs = B[1 + ph], he = B[8 + ph];   // wave-uniform scalars
        float4 acc = make_float4(-FLT_MAX, -FLT_MAX, -FLT_MAX, -FLT_MAX);
        if (hs < he) {
            int idx = base + (hs << 4);
            float4 v = f4[idx];
            for (int h = hs + 1; h < he; ++h) {   // 1-deep prefetch
                idx += 16;
                float4 vn = f4[idx];
                acc = max4(acc, v);
                v = vn;
            }
            acc = max4(acc, v);
        }
        *(float4*)&cm[chl][ph][cq << 2] = acc;
    }

    // Epilogue (wave-private, no block barrier): 4 ch * 49 bins = 196 outputs.
    size_t obase = ((size_t)(r << 9) + c0) * 49;
    #pragma unroll
    for (int it = 0; it < 4; ++it) {
        int f = (it << 6) + lane;
        if (f < 4 * 49) {
            int ch = f / 49;
            int i  = f - ch * 49;
            int ph = i / 7;
            int pw = i - ph * 7;
            int hs  = B[1 + ph],  he  = B[8 + ph];    // L2-hot vector loads
            int wst = B[15 + pw], wen = B[22 + pw];
            float m = -FLT_MAX;
            for (int w = wst; w < wen; ++w)
                m = fmaxf(m, cm[(wv << 2) + ch][ph][w]);
            bool empty = (he <= hs) || (wen <= wst);
            __builtin_nontemporal_store(empty ? 0.0f : m, &out[obase + f]);
        }
    }
}

extern "C" void kernel_launch(void* const* d_in, const int* in_sizes, int n_in,
                              void* d_out, int out_size, void* d_ws, size_t ws_size,
                              hipStream_t stream) {
    const float* features = (const float*)d_in[0];
    const float* rois     = (const float*)d_in[1];
    float* out = (float*)d_out;
    int* wsbuf = (int*)d_ws;

    int R = in_sizes[1] / 5;   // 2000

    roi_bounds_kernel<<<(R + 255) / 256, 256, 0, stream>>>(rois, wsbuf, R);
    roipool_main<<<R * 64, 128, 0, stream>>>(features, wsbuf, out);
}

// Round 8
// 311.444 us; speedup vs baseline: 2.4224x; 1.4154x over previous
//
#include <hip/hip_runtime.h>
#include <math.h>
#include <float.h>

#define PH 7
#define RLEN 80   // ints per roi in workspace

// ---- exact integer emulation of the reference's fast-math f32 binning ----
// bin = RN_f32(roi * RN_f32(1/7));  RN_f32(1/7) = 9586981 * 2^-26
#define C7 9586981LL

__device__ __forceinline__ long long round24(long long v) {
    if (v == 0) return 0;
    int L = 64 - __clzll((unsigned long long)v);
    int sh = L - 24;
    if (sh <= 0) return v;
    long long rem  = v & ((1LL << sh) - 1);
    long long base = v >> sh;
    long long half = 1LL << (sh - 1);
    if (rem > half || (rem == half && (base & 1))) base++;
    return base << sh;
}
__device__ __forceinline__ long long bin_q26(int roi) {
    return round24((long long)roi * C7);
}
__device__ __forceinline__ int floor_k(long long b26, int k) {
    long long v = round24((long long)k * b26);
    return (int)(v >> 26);
}
__device__ __forceinline__ int ceil_k(long long b26, int k) {
    long long v = round24((long long)k * b26);
    return (int)((v + ((1LL << 26) - 1)) >> 26);
}

// Per-ROI bounds. Layout (ints): [0]=b, [1..7]=hstart, [8..14]=hend,
// [16+i] i<49: packed per-bin  hs | he<<7 | ws<<14 | we<<21 | ph<<28
__global__ void roi_bounds_kernel(const float* __restrict__ rois,
                                  int* __restrict__ wsbuf, int R) {
    int r = blockIdx.x * blockDim.x + threadIdx.x;
    if (r >= R) return;
    const int H = 64, W = 64;
    const float* roi = rois + r * 5;
    int b  = (int)roi[0];
    int x1 = (int)rintf(roi[1] * 0.0625f);
    int y1 = (int)rintf(roi[2] * 0.0625f);
    int x2 = (int)rintf(roi[3] * 0.0625f);
    int y2 = (int)rintf(roi[4] * 0.0625f);

    int roi_w = max(x2 - x1 + 1, 1);
    int roi_h = max(y2 - y1 + 1, 1);
    long long bh = bin_q26(roi_h);
    long long bw = bin_q26(roi_w);

    int hs[PH], he[PH], ws[PH], we[PH];
    #pragma unroll
    for (int i = 0; i < PH; ++i) {
        hs[i] = min(max(y1 + floor_k(bh, i),     0), H);
        he[i] = min(max(y1 + ceil_k (bh, i + 1), 0), H);
        ws[i] = min(max(x1 + floor_k(bw, i),     0), W);
        we[i] = min(max(x1 + ceil_k (bw, i + 1), 0), W);
    }

    int* o = wsbuf + r * RLEN;
    o[0] = b;
    #pragma unroll
    for (int i = 0; i < PH; ++i) { o[1 + i] = hs[i]; o[8 + i] = he[i]; }
    #pragma unroll
    for (int ph = 0; ph < PH; ++ph)
        #pragma unroll
        for (int pw = 0; pw < PH; ++pw)
            o[16 + ph * 7 + pw] =
                hs[ph] | (he[ph] << 7) | (ws[pw] << 14) | (we[pw] << 21) | (ph << 28);
}

// One wave = 4 channels of one roi. lane = chsub*16 + cq.
// One dwordx4 load per row-iter covers 64 cols x 4 channels.
__global__ __launch_bounds__(128) void roipool_main(
        const float* __restrict__ features,
        const int* __restrict__ wsbuf,
        float* __restrict__ out) {
    __shared__ float cm[8][PH][68];   // 68: ph-rows 17 banks apart, 16B-aligned

    int r    = blockIdx.x >> 6;
    int cg   = blockIdx.x & 63;
    int wv   = threadIdx.x >> 6;
    int lane = threadIdx.x & 63;
    int chsub = lane >> 4;
    int cq    = lane & 15;
    int c0   = (cg << 3) + (wv << 2);

    const int* B = wsbuf + r * RLEN;   // wave-uniform -> scalar loads
    int b = B[0];

    const float4* f4 = (const float4*)features;
    int base = (((b << 9) + c0 + chsub) << 10) | cq;
    int chl  = (wv << 2) + chsub;

    // packed per-bin bounds, one coalesced load (lanes 0..48)
    int pb = B[16 + (lane < 49 ? lane : 48)];
    int pbhs = pb & 127, pbhe = (pb >> 7) & 127;
    int pbws = (pb >> 14) & 127, pbwe = (pb >> 21) & 127;
    int pbph = ((unsigned)pb) >> 28;

    #pragma unroll
    for (int ph = 0; ph < PH; ++ph) {
        int hs = B[1 + ph], he = B[8 + ph];
        float4 acc = make_float4(-FLT_MAX, -FLT_MAX, -FLT_MAX, -FLT_MAX);
        int n = he - hs;
        int idx = base + (hs << 4);
        while (n >= 2) {                      // 2 loads in flight, max3 fusion
            float4 v0 = f4[idx];
            float4 v1 = f4[idx + 16];
            acc.x = fmaxf(fmaxf(acc.x, v0.x), v1.x);
            acc.y = fmaxf(fmaxf(acc.y, v0.y), v1.y);
            acc.z = fmaxf(fmaxf(acc.z, v0.z), v1.z);
            acc.w = fmaxf(fmaxf(acc.w, v0.w), v1.w);
            idx += 32; n -= 2;
        }
        if (n) {
            float4 v0 = f4[idx];
            acc.x = fmaxf(acc.x, v0.x); acc.y = fmaxf(acc.y, v0.y);
            acc.z = fmaxf(acc.z, v0.z); acc.w = fmaxf(acc.w, v0.w);
        }
        *(float4*)&cm[chl][ph][cq << 2] = acc;
    }
    // no barrier: cm region is wave-private

    size_t obase = ((size_t)(r << 9) + c0) * 49;
    bool empty = (pbhe <= pbhs) || (pbwe <= pbws);
    #pragma unroll
    for (int it = 0; it < 4; ++it) {
        if (lane < 49) {
            const float* row = &cm[(wv << 2) + it][pbph][0];
            float m = -FLT_MAX;
            int w = pbws;
            for (; w + 2 <= pbwe; w += 2)
                m = fmaxf(fmaxf(m, row[w]), row[w + 1]);
            if (w < pbwe) m = fmaxf(m, row[w]);
            out[obase + it * 49 + lane] = empty ? 0.0f : m;
        }
    }
}

extern "C" void kernel_launch(void* const* d_in, const int* in_sizes, int n_in,
                              void* d_out, int out_size, void* d_ws, size_t ws_size,
                              hipStream_t stream) {
    const float* features = (const float*)d_in[0];
    const float* rois     = (const float*)d_in[1];
    float* out = (float*)d_out;
    int* wsbuf = (int*)d_ws;

    int R = in_sizes[1] / 5;   // 2000

    roi_bounds_kernel<<<(R + 255) / 256, 256, 0, stream>>>(rois, wsbuf, R);
    roipool_main<<<R * 64, 128, 0, stream>>>(features, wsbuf, out);
}